// Round 4
// baseline (831.269 us; speedup 1.0000x reference)
//
#include <hip/hip_runtime.h>

typedef unsigned short u16;
typedef __attribute__((ext_vector_type(8))) short short8;
typedef __attribute__((ext_vector_type(4))) float f32x4;

// ---- ws layout (bytes) ----  peak = 203,657,216 B (~194.2 MiB)
#define OFF_SUMS 0ul              // 3072 floats = 12288
#define OFF_WT   12288ul          // 110592*2 = 221184 : weights bf16 [dydx][192 oc][64 c]
#define OFF_ASP  233472ul         // 524288*4 = 2097152 : attn_spatial fp32 [pixel]
#define OFF_CONV 2330624ul        // 524288*192*2 = 201326592 : raw conv out bf16 [pixel][192]
// xt (x in NHWC bf16, 67108864 B) lives in the first half of d_out (fp32 out = 134217728 B);
// k6 fully overwrites d_out at the end.
// ---- S (float) offsets ----
#define S_SUM  0
#define S_SSQ  192
#define S_SC   384
#define S_BI   576
#define S_CH1  768
#define S_CH23 1280
#define S_CH45 1792
#define S_ACH  2304
#define S_ASUM 2816
#define S_ASSQ 2880
#define S_SCA  2944
#define S_BIA  3008

__device__ __forceinline__ float bf2f(u16 v) {
  union { unsigned u; float f; } x; x.u = ((unsigned)v) << 16; return x.f;
}
__device__ __forceinline__ u16 f2bf(float f) {
  union { float f; unsigned u; } x; x.f = f;
  unsigned r = x.u + 0x7fffu + ((x.u >> 16) & 1u);
  return (u16)(r >> 16);
}
__device__ __forceinline__ float sigmoidf_(float x) { return 1.f / (1.f + __expf(-x)); }

// ---------------- K0a: NCHW fp32 -> NHWC bf16 transpose of x (into d_out scratch) ----------------
__global__ void transpose_k(const float* __restrict__ x, u16* __restrict__ xt) {
  __shared__ u16 t[64][130];
  const int bid = blockIdx.x;
  const int wtile = bid & 1, h = (bid >> 1) & 255, n = bid >> 9;
  const int w0 = wtile << 7;
  const int tid = threadIdx.x;
  for (int i = tid; i < 8192; i += 256) {
    int c = i >> 7, w = i & 127;
    t[c][w] = f2bf(x[(((n << 6) + c) << 16) + (h << 8) + w0 + w]);
  }
  __syncthreads();
  for (int i = tid; i < 8192; i += 256) {
    int w = i >> 6, c = i & 63;
    xt[(long)((((n << 8) + h) << 8) + w0 + w) * 64 + c] = t[c][w];
  }
}

// ---------------- K0b: weight repack fp32 -> bf16 [dydx][conv*64+oc][c] ----------------
__global__ void repack_k(const float* __restrict__ wq, const float* __restrict__ wk,
                         const float* __restrict__ wv, u16* __restrict__ wt) {
  int i = blockIdx.x * 256 + threadIdx.x;
  if (i >= 110592) return;
  int conv = i / 36864, j = i % 36864;
  int oc = j / 576, r2 = j % 576, c = r2 / 9, dd = r2 % 9;
  const float* src = conv == 0 ? wq : (conv == 1 ? wk : wv);
  wt[(dd * 192 + conv * 64 + oc) * 64 + c] = f2bf(src[j]);
}

// ---------------- K1: fused QKV conv3x3 as implicit GEMM (MFMA bf16) ----------------
// block: 128 pixels (one (n,h) half-row) x 192 oc. 4 waves x (8 m-tiles x 3 n-tiles).
__global__ __launch_bounds__(256, 2) void conv_k(const u16* __restrict__ xt,
                                                 const u16* __restrict__ wt,
                                                 u16* __restrict__ conv) {
  __shared__ u16 lx[3 * 130 * 72];  // pixel stride 72 (144B = 9*16B)
  const int bid = blockIdx.x;
  const int wtile = bid & 1, h = (bid >> 1) & 255, n = bid >> 9;
  const int w0 = wtile << 7;
  const int tid = threadIdx.x;
  // stage 3 rows x 130 w x 64 c, zero halo
  for (int g = tid; g < 3120; g += 256) {
    int row = g / 1040;
    int r2 = g - row * 1040;
    int w = r2 >> 3, cg = r2 & 7;
    int hs = h + row - 1, wsr = w0 + w - 1;
    uint4 val = make_uint4(0u, 0u, 0u, 0u);
    if ((unsigned)hs < 256u && (unsigned)wsr < 256u)
      val = *(const uint4*)(xt + (long)((((n << 8) + hs) << 8) + wsr) * 64 + (cg << 3));
    *(uint4*)(&lx[row * 9360 + w * 72 + (cg << 3)]) = val;
  }
  __syncthreads();
  const int lane = tid & 63, wave = tid >> 6;
  const int quad = lane >> 4, l15 = lane & 15;
  f32x4 acc[3][8];
#pragma unroll
  for (int a = 0; a < 3; ++a)
#pragma unroll
    for (int b = 0; b < 8; ++b) acc[a][b] = (f32x4){0.f, 0.f, 0.f, 0.f};

#pragma unroll
  for (int dy = 0; dy < 3; ++dy) {
#pragma unroll
    for (int dx = 0; dx < 3; ++dx) {
      const u16* wp = wt + (dy * 3 + dx) * 12288;
      short8 bfr[3][2];
#pragma unroll
      for (int nt = 0; nt < 3; ++nt)
#pragma unroll
        for (int kc = 0; kc < 2; ++kc)
          bfr[nt][kc] = *(const short8*)(wp + ((wave * 3 + nt) * 16 + l15) * 64 + kc * 32 + quad * 8);
#pragma unroll
      for (int kc = 0; kc < 2; ++kc) {
        short8 afr[8];
#pragma unroll
        for (int mt = 0; mt < 8; ++mt)
          afr[mt] = *(const short8*)(&lx[dy * 9360 + (mt * 16 + l15 + dx) * 72 + kc * 32 + quad * 8]);
#pragma unroll
        for (int mt = 0; mt < 8; ++mt)
#pragma unroll
          for (int nt = 0; nt < 3; ++nt)
            acc[nt][mt] = __builtin_amdgcn_mfma_f32_16x16x32_bf16(afr[mt], bfr[nt][kc], acc[nt][mt], 0, 0, 0);
      }
    }
  }
  // epilogue: D row = quad*4+r (pixel), col = l15 (oc); store bf16 [pixel][192]
  const long pix0 = (long)bid * 128;
#pragma unroll
  for (int nt = 0; nt < 3; ++nt) {
    const int oc = (wave * 3 + nt) * 16 + l15;
#pragma unroll
    for (int mt = 0; mt < 8; ++mt) {
      const long pr = pix0 + mt * 16 + quad * 4;
#pragma unroll
      for (int r = 0; r < 4; ++r)
        conv[(pr + r) * 192 + oc] = f2bf(acc[nt][mt][r]);
    }
  }
}

// ---------------- K2a: per-channel sum/sumsq over all pixels (192 ch) ----------------
__global__ void bnstat_k(const u16* __restrict__ conv, float* __restrict__ S) {
  const int t = threadIdx.x;  // 192
  const long p0 = (long)blockIdx.x * 512;
  float s = 0.f, ss = 0.f;
  for (int i = 0; i < 512; ++i) {
    float v = bf2f(conv[(p0 + i) * 192 + t]);
    s += v; ss += v * v;
  }
  atomicAdd(&S[S_SUM + t], s);
  atomicAdd(&S[S_SSQ + t], ss);
}

// ---------------- K2b: BN scale/bias for q,k,v ----------------
__global__ void bnparam_k(float* __restrict__ S, const float* gq, const float* bq, const float* gk,
                          const float* bk, const float* gv, const float* bv) {
  int t = threadIdx.x;  // 192
  int cv = t >> 6, c = t & 63;
  float g = cv == 0 ? gq[c] : (cv == 1 ? gk[c] : gv[c]);
  float b = cv == 0 ? bq[c] : (cv == 1 ? bk[c] : bv[c]);
  const float inv = 1.f / 524288.f;
  float mean = S[S_SUM + t] * inv;
  float var = S[S_SSQ + t] * inv - mean * mean;
  float rstd = rsqrtf(var + 1e-5f);
  float sc = g * rstd;
  S[S_SC + t] = sc;
  S[S_BI + t] = b - mean * sc;
}

// ---------------- K3: BN+sigmoid on q,k; attn_spatial per pixel; per-(n,c) sums ----------------
__global__ void k3_k(const u16* __restrict__ conv, float* __restrict__ S, float* __restrict__ asp) {
  const int tid = threadIdx.x, lane = tid & 63, wave = tid >> 6;
  const int n = blockIdx.x >> 7, chunk = blockIdx.x & 127;
  const long p0 = (long)n * 65536 + chunk * 512 + wave * 128;
  const float sq = S[S_SC + lane], bq = S[S_BI + lane];
  const float sk = S[S_SC + 64 + lane], bk = S[S_BI + 64 + lane];
  float a1 = 0.f, a23 = 0.f, a45 = 0.f;
  for (int i = 0; i < 128; ++i) {
    const long p = p0 + i;
    const u16* row = conv + p * 192;
    float q = sigmoidf_(bf2f(row[lane]) * sq + bq);
    float k = sigmoidf_(bf2f(row[64 + lane]) * sk + bk);
    float s1 = q * k, s23 = q * q + k * k, s45 = q + k;
    a1 += s1; a23 += s23; a45 += s45;
#pragma unroll
    for (int off = 32; off > 0; off >>= 1) {
      s1 += __shfl_down(s1, off);
      s23 += __shfl_down(s23, off);
      s45 += __shfl_down(s45, off);
    }
    if (lane == 0) {
      const float sm = 1e-5f;
      float t1 = (s1 + sm) / (s23 - s1 + sm);
      float t2 = (64.f - s45 + s1 + sm) / (64.f - s45 + s23 - s1 + sm);
      asp[p] = 0.5f * (t1 + t2);
    }
  }
  atomicAdd(&S[S_CH1 + n * 64 + lane], a1);
  atomicAdd(&S[S_CH23 + n * 64 + lane], a23);
  atomicAdd(&S[S_CH45 + n * 64 + lane], a45);
}

// ---------------- K4: attn_channel per (n,c) ----------------
__global__ void k4_k(float* __restrict__ S) {
  int t = threadIdx.x;  // 512
  float S1 = S[S_CH1 + t], S23 = S[S_CH23 + t], S45 = S[S_CH45 + t];
  const float sm = 1e-5f, cnt = 65536.f;
  float t1 = (S1 + sm) / (S23 - S1 + sm);
  float t2 = (cnt - S45 + S1 + sm) / (cnt - S45 + S23 - S1 + sm);
  S[S_ACH + t] = 0.5f * (t1 + t2);
}

// ---------------- K5: attention stats (per final-BN channel) ----------------
__global__ void k5_k(const u16* __restrict__ conv, float* __restrict__ S,
                     const float* __restrict__ asp) {
  const int tid = threadIdx.x, lane = tid & 63, wave = tid >> 6;
  const int n = blockIdx.x >> 7, chunk = blockIdx.x & 127;
  const long p0 = (long)n * 65536 + chunk * 512 + wave * 128;
  const float sv = S[S_SC + 128 + lane], bv = S[S_BI + 128 + lane];
  const float av = S[S_ACH + n * 64 + lane];
  float s = 0.f, ss = 0.f;
  for (int i = 0; i < 128; ++i) {
    const long p = p0 + i;
    float v = sigmoidf_(bf2f(conv[p * 192 + 128 + lane]) * sv + bv);
    float att = 0.5f * (asp[p] + av) * v;
    s += att; ss += att * att;
  }
  atomicAdd(&S[S_ASUM + lane], s);
  atomicAdd(&S[S_ASSQ + lane], ss);
}

// ---------------- K5b: final BN params ----------------
__global__ void k5b_k(float* __restrict__ S, const float* gn, const float* bn_) {
  int c = threadIdx.x;  // 64
  const float inv = 1.f / 524288.f;
  float mean = S[S_ASUM + c] * inv;
  float var = S[S_ASSQ + c] * inv - mean * mean;
  float rstd = rsqrtf(var + 1e-5f);
  float sc = gn[c] * rstd;
  S[S_SCA + c] = sc;
  S[S_BIA + c] = bn_[c] - mean * sc;
}

// ---------------- K6: attention -> final BN -> NCHW fp32 out (LDS transpose) ----------------
__global__ void k6_k(const u16* __restrict__ conv, const float* __restrict__ S,
                     const float* __restrict__ asp, float* __restrict__ out) {
  __shared__ float t[128][65];  // 33280 B
  const int tid = threadIdx.x, lane = tid & 63, wave = tid >> 6;
  const int n = blockIdx.x >> 9;
  const int hw0 = (blockIdx.x & 511) << 7;
  const long P0 = (long)blockIdx.x * 128;
  const float sv = S[S_SC + 128 + lane], bv = S[S_BI + 128 + lane];
  const float av = S[S_ACH + n * 64 + lane];
  const float sA = S[S_SCA + lane], bA = S[S_BIA + lane];
  for (int i = wave; i < 128; i += 4) {
    const long p = P0 + i;
    float v = sigmoidf_(bf2f(conv[p * 192 + 128 + lane]) * sv + bv);
    float att = 0.5f * (asp[p] + av) * v;
    t[i][lane] = att * sA + bA;
  }
  __syncthreads();
  const int c = tid >> 2, sub = tid & 3;
  const long plane = ((long)((n << 6) + c)) << 16;
  for (int i = 0; i < 8; ++i) {
    const int pst = (i * 4 + sub) << 2;
    f32x4 vbuf;
#pragma unroll
    for (int j = 0; j < 4; ++j) vbuf[j] = t[pst + j][c];
    *(f32x4*)(&out[plane + hw0 + pst]) = vbuf;
  }
}

extern "C" void kernel_launch(void* const* d_in, const int* in_sizes, int n_in,
                              void* d_out, int out_size, void* d_ws, size_t ws_size,
                              hipStream_t stream) {
  (void)in_sizes; (void)n_in; (void)out_size; (void)ws_size;
  const float* x  = (const float*)d_in[0];
  const float* wq = (const float*)d_in[1];
  const float* gq = (const float*)d_in[2];
  const float* bq = (const float*)d_in[3];
  const float* wk = (const float*)d_in[4];
  const float* gk = (const float*)d_in[5];
  const float* bk = (const float*)d_in[6];
  const float* wv = (const float*)d_in[7];
  const float* gv = (const float*)d_in[8];
  const float* bv = (const float*)d_in[9];
  const float* gn = (const float*)d_in[10];
  const float* bn_ = (const float*)d_in[11];
  char* ws = (char*)d_ws;
  float* S   = (float*)(ws + OFF_SUMS);
  u16* wt    = (u16*)(ws + OFF_WT);
  float* asp = (float*)(ws + OFF_ASP);
  u16* conv  = (u16*)(ws + OFF_CONV);
  float* out = (float*)d_out;
  u16* xt  = (u16*)d_out;  // bf16 NHWC scratch in first half of fp32 out; overwritten by k6_k

  hipMemsetAsync(S, 0, 12288, stream);
  transpose_k<<<4096, 256, 0, stream>>>(x, xt);
  repack_k<<<432, 256, 0, stream>>>(wq, wk, wv, wt);
  conv_k<<<4096, 256, 0, stream>>>(xt, wt, conv);
  bnstat_k<<<1024, 192, 0, stream>>>(conv, S);
  bnparam_k<<<1, 192, 0, stream>>>(S, gq, bq, gk, bk, gv, bv);
  k3_k<<<1024, 256, 0, stream>>>(conv, S, asp);
  k4_k<<<1, 512, 0, stream>>>(S);
  k5_k<<<1024, 256, 0, stream>>>(conv, S, asp);
  k5b_k<<<1, 64, 0, stream>>>(S, gn, bn_);
  k6_k<<<4096, 256, 0, stream>>>(conv, S, asp, out);
}

// Round 5
// 612.930 us; speedup vs baseline: 1.3562x; 1.3562x over previous
//
#include <hip/hip_runtime.h>

typedef unsigned short u16;
typedef __attribute__((ext_vector_type(8))) short short8;
typedef __attribute__((ext_vector_type(4))) float f32x4;

// ---- ws layout (bytes) ----
#define OFF_SUMS 0ul              // 6656 floats = 26624
#define OFF_WT   26624ul          // 110592*2 = 221184 : weights bf16 [dydx][192 oc][64 c]
#define OFF_ASP  247808ul         // 524288*4 = 2097152 : attn_spatial fp32 [pixel]
#define OFF_CONV 2344960ul        // 524288*192*2 = 201326592 : raw conv out bf16 [pixel][192]
// xt (NHWC bf16, 67 MB) lives in first half of d_out (fp32, 134 MB); k6 overwrites it.
// ---- S (float) offsets ----
#define S_SUM   0      // conv channel sums, 4 shadows x 192
#define S_SSQ   768    // conv channel ssq, 4 shadows x 192
#define S_SC    1536   // 192
#define S_BI    1728   // 192
#define M_A1    1920   // per (n*64+c): sum q*k        [512]
#define M_A23   2432   // sum q^2+k^2                  [512]
#define M_A45   2944   // sum q+k                      [512]
#define M_V1    3456   // sum v                        [512]
#define M_V2    3968   // sum v^2                      [512]
#define M_AV    4480   // sum asp*v                    [512]
#define M_AV2   4992   // sum asp*v^2                  [512]
#define M_A2V2  5504   // sum asp^2*v^2                [512]
#define S_ACH   6016   // attn_channel per (n,c)       [512]
#define S_SCA   6528   // final BN scale               [64]
#define S_BIA   6592   // final BN bias                [64]
#define S_NFLOAT 6656

__device__ __forceinline__ float bf2f(u16 v) {
  union { unsigned u; float f; } x; x.u = ((unsigned)v) << 16; return x.f;
}
__device__ __forceinline__ u16 f2bf(float f) {
  union { float f; unsigned u; } x; x.f = f;
  unsigned r = x.u + 0x7fffu + ((x.u >> 16) & 1u);
  return (u16)(r >> 16);
}
__device__ __forceinline__ float sigmoidf_(float x) { return 1.f / (1.f + __expf(-x)); }

// ---------------- K0a: NCHW fp32 -> NHWC bf16 transpose of x (into d_out scratch) ----------------
__global__ void transpose_k(const float* __restrict__ x, u16* __restrict__ xt) {
  __shared__ u16 t[64][130];
  const int bid = blockIdx.x;
  const int wtile = bid & 1, h = (bid >> 1) & 255, n = bid >> 9;
  const int w0 = wtile << 7;
  const int tid = threadIdx.x;
  for (int i = tid; i < 8192; i += 256) {
    int c = i >> 7, w = i & 127;
    t[c][w] = f2bf(x[(((n << 6) + c) << 16) + (h << 8) + w0 + w]);
  }
  __syncthreads();
  for (int i = tid; i < 8192; i += 256) {
    int w = i >> 6, c = i & 63;
    xt[(long)((((n << 8) + h) << 8) + w0 + w) * 64 + c] = t[c][w];
  }
}

// ---------------- K0b: weight repack fp32 -> bf16 [dydx][conv*64+oc][c] ----------------
__global__ void repack_k(const float* __restrict__ wq, const float* __restrict__ wk,
                         const float* __restrict__ wv, u16* __restrict__ wt) {
  int i = blockIdx.x * 256 + threadIdx.x;
  if (i >= 110592) return;
  int conv = i / 36864, j = i % 36864;
  int oc = j / 576, r2 = j % 576, c = r2 / 9, dd = r2 % 9;
  const float* src = conv == 0 ? wq : (conv == 1 ? wk : wv);
  wt[(dd * 192 + conv * 64 + oc) * 64 + c] = f2bf(src[j]);
}

// ---------------- K1: fused QKV conv3x3 as implicit GEMM (MFMA bf16) + channel stats ----------------
__global__ __launch_bounds__(256, 2) void conv_k(const u16* __restrict__ xt,
                                                 const u16* __restrict__ wt,
                                                 u16* __restrict__ conv,
                                                 float* __restrict__ S) {
  __shared__ u16 lx[3 * 130 * 72];  // pixel stride 72 (144B = 9*16B)
  const int bid = blockIdx.x;
  const int wtile = bid & 1, h = (bid >> 1) & 255, n = bid >> 9;
  const int w0 = wtile << 7;
  const int tid = threadIdx.x;
  for (int g = tid; g < 3120; g += 256) {
    int row = g / 1040;
    int r2 = g - row * 1040;
    int w = r2 >> 3, cg = r2 & 7;
    int hs = h + row - 1, wsr = w0 + w - 1;
    uint4 val = make_uint4(0u, 0u, 0u, 0u);
    if ((unsigned)hs < 256u && (unsigned)wsr < 256u)
      val = *(const uint4*)(xt + (long)((((n << 8) + hs) << 8) + wsr) * 64 + (cg << 3));
    *(uint4*)(&lx[row * 9360 + w * 72 + (cg << 3)]) = val;
  }
  __syncthreads();
  const int lane = tid & 63, wave = tid >> 6;
  const int quad = lane >> 4, l15 = lane & 15;
  f32x4 acc[3][8];
#pragma unroll
  for (int a = 0; a < 3; ++a)
#pragma unroll
    for (int b = 0; b < 8; ++b) acc[a][b] = (f32x4){0.f, 0.f, 0.f, 0.f};

#pragma unroll
  for (int dy = 0; dy < 3; ++dy) {
#pragma unroll
    for (int dx = 0; dx < 3; ++dx) {
      const u16* wp = wt + (dy * 3 + dx) * 12288;
      short8 bfr[3][2];
#pragma unroll
      for (int nt = 0; nt < 3; ++nt)
#pragma unroll
        for (int kc = 0; kc < 2; ++kc)
          bfr[nt][kc] = *(const short8*)(wp + ((wave * 3 + nt) * 16 + l15) * 64 + kc * 32 + quad * 8);
#pragma unroll
      for (int kc = 0; kc < 2; ++kc) {
        short8 afr[8];
#pragma unroll
        for (int mt = 0; mt < 8; ++mt)
          afr[mt] = *(const short8*)(&lx[dy * 9360 + (mt * 16 + l15 + dx) * 72 + kc * 32 + quad * 8]);
#pragma unroll
        for (int mt = 0; mt < 8; ++mt)
#pragma unroll
          for (int nt = 0; nt < 3; ++nt)
            acc[nt][mt] = __builtin_amdgcn_mfma_f32_16x16x32_bf16(afr[mt], bfr[nt][kc], acc[nt][mt], 0, 0, 0);
      }
    }
  }
  // epilogue: D row = quad*4+r (pixel), col = l15 (oc); store bf16 [pixel][192]
  const long pix0 = (long)bid * 128;
#pragma unroll
  for (int nt = 0; nt < 3; ++nt) {
    const int oc = (wave * 3 + nt) * 16 + l15;
#pragma unroll
    for (int mt = 0; mt < 8; ++mt) {
      const long pr = pix0 + mt * 16 + quad * 4;
#pragma unroll
      for (int r = 0; r < 4; ++r)
        conv[(pr + r) * 192 + oc] = f2bf(acc[nt][mt][r]);
    }
  }
  // fused per-channel stats: each lane's 32 pixels -> quad-reduce -> shadowed atomics
  const int sh = (bid & 3) * 192;
#pragma unroll
  for (int nt = 0; nt < 3; ++nt) {
    float s = 0.f, ss = 0.f;
#pragma unroll
    for (int mt = 0; mt < 8; ++mt)
#pragma unroll
      for (int r = 0; r < 4; ++r) {
        float x = acc[nt][mt][r];
        s += x; ss += x * x;
      }
    s += __shfl_xor(s, 16); ss += __shfl_xor(ss, 16);
    s += __shfl_xor(s, 32); ss += __shfl_xor(ss, 32);
    if (lane < 16) {
      const int oc = (wave * 3 + nt) * 16 + l15;
      atomicAdd(&S[S_SUM + sh + oc], s);
      atomicAdd(&S[S_SSQ + sh + oc], ss);
    }
  }
}

// ---------------- K2b: BN scale/bias for q,k,v ----------------
__global__ void bnparam_k(float* __restrict__ S, const float* gq, const float* bq, const float* gk,
                          const float* bk, const float* gv, const float* bv) {
  int t = threadIdx.x;  // 192
  int cv = t >> 6, c = t & 63;
  float g = cv == 0 ? gq[c] : (cv == 1 ? gk[c] : gv[c]);
  float b = cv == 0 ? bq[c] : (cv == 1 ? bk[c] : bv[c]);
  float sm = 0.f, sq = 0.f;
#pragma unroll
  for (int sh = 0; sh < 4; ++sh) { sm += S[S_SUM + sh * 192 + t]; sq += S[S_SSQ + sh * 192 + t]; }
  const float inv = 1.f / 524288.f;
  float mean = sm * inv;
  float var = sq * inv - mean * mean;
  float rstd = rsqrtf(var + 1e-5f);
  float sc = g * rstd;
  S[S_SC + t] = sc;
  S[S_BI + t] = b - mean * sc;
}

// ---------------- K3: BN+sigmoid q,k,v; asp per pixel; 8 moments per (n,c) ----------------
__global__ void k3_k(const u16* __restrict__ conv, float* __restrict__ S, float* __restrict__ asp) {
  __shared__ float red[4][8][64];
  const int tid = threadIdx.x, lane = tid & 63, wave = tid >> 6;
  const int bid = blockIdx.x;          // 4096 blocks x 128 px
  const int n = bid >> 9;
  const long p0 = (long)bid * 128 + wave * 32;
  const float sq = S[S_SC + lane], bq = S[S_BI + lane];
  const float sk = S[S_SC + 64 + lane], bk = S[S_BI + 64 + lane];
  const float sv = S[S_SC + 128 + lane], bv = S[S_BI + 128 + lane];
  float A1 = 0.f, A23 = 0.f, A45 = 0.f, V1 = 0.f, V2 = 0.f, AV = 0.f, AV2 = 0.f, A2V2 = 0.f;
  float myasp = 0.f;
#pragma unroll 4
  for (int i = 0; i < 32; ++i) {
    const u16* row = conv + (p0 + i) * 192;
    float q = sigmoidf_(bf2f(row[lane]) * sq + bq);
    float k = sigmoidf_(bf2f(row[64 + lane]) * sk + bk);
    float v = sigmoidf_(bf2f(row[128 + lane]) * sv + bv);
    float s1 = q * k, s23 = q * q + k * k, s45 = q + k;
    A1 += s1; A23 += s23; A45 += s45;
#pragma unroll
    for (int m = 1; m < 64; m <<= 1) {
      s1 += __shfl_xor(s1, m);
      s23 += __shfl_xor(s23, m);
      s45 += __shfl_xor(s45, m);
    }
    const float sm = 1e-5f;
    float t1 = (s1 + sm) / (s23 - s1 + sm);
    float t2 = (64.f - s45 + s1 + sm) / (64.f - s45 + s23 - s1 + sm);
    float a = 0.5f * (t1 + t2);
    if (i == (lane & 31)) myasp = a;
    float av = a * v;
    V1 += v; V2 += v * v; AV += av; AV2 += av * v; A2V2 += av * av;
  }
  if (lane < 32) asp[p0 + lane] = myasp;
  red[wave][0][lane] = A1;  red[wave][1][lane] = A23; red[wave][2][lane] = A45;
  red[wave][3][lane] = V1;  red[wave][4][lane] = V2;  red[wave][5][lane] = AV;
  red[wave][6][lane] = AV2; red[wave][7][lane] = A2V2;
  __syncthreads();
  if (tid < 64) {
    const int mb[8] = {M_A1, M_A23, M_A45, M_V1, M_V2, M_AV, M_AV2, M_A2V2};
#pragma unroll
    for (int m = 0; m < 8; ++m) {
      float t = red[0][m][tid] + red[1][m][tid] + red[2][m][tid] + red[3][m][tid];
      atomicAdd(&S[mb[m] + n * 64 + tid], t);
    }
  }
}

// ---------------- K4: attn_channel per (n,c) + final BN params ----------------
__global__ void k4_k(float* __restrict__ S, const float* gn, const float* bn_) {
  __shared__ float r1[512], r2[512];
  const int t = threadIdx.x;  // 512 = (n,c)
  float A1 = S[M_A1 + t], A23 = S[M_A23 + t], A45 = S[M_A45 + t];
  const float sm = 1e-5f, cnt = 65536.f;
  float t1 = (A1 + sm) / (A23 - A1 + sm);
  float t2 = (cnt - A45 + A1 + sm) / (cnt - A45 + A23 - A1 + sm);
  float ach = 0.5f * (t1 + t2);
  S[S_ACH + t] = ach;
  r1[t] = 0.5f * (S[M_AV + t] + ach * S[M_V1 + t]);
  r2[t] = 0.25f * (S[M_A2V2 + t] + 2.f * ach * S[M_AV2 + t] + ach * ach * S[M_V2 + t]);
  __syncthreads();
  if (t < 64) {
    float s = 0.f, ss = 0.f;
#pragma unroll
    for (int n = 0; n < 8; ++n) { s += r1[n * 64 + t]; ss += r2[n * 64 + t]; }
    const float inv = 1.f / 524288.f;
    float mean = s * inv;
    float var = ss * inv - mean * mean;
    float rstd = rsqrtf(var + 1e-5f);
    float sc = gn[t] * rstd;
    S[S_SCA + t] = sc;
    S[S_BIA + t] = bn_[t] - mean * sc;
  }
}

// ---------------- K6: attention -> final BN -> NCHW fp32 out (LDS transpose) ----------------
__global__ void k6_k(const u16* __restrict__ conv, const float* __restrict__ S,
                     const float* __restrict__ asp, float* __restrict__ out) {
  __shared__ float t[128][65];
  const int tid = threadIdx.x, lane = tid & 63, wave = tid >> 6;
  const int n = blockIdx.x >> 9;
  const int hw0 = (blockIdx.x & 511) << 7;
  const long P0 = (long)blockIdx.x * 128;
  const float sv = S[S_SC + 128 + lane], bv = S[S_BI + 128 + lane];
  const float av = S[S_ACH + n * 64 + lane];
  const float sA = S[S_SCA + lane], bA = S[S_BIA + lane];
  for (int i = wave; i < 128; i += 4) {
    const long p = P0 + i;
    float v = sigmoidf_(bf2f(conv[p * 192 + 128 + lane]) * sv + bv);
    float att = 0.5f * (asp[p] + av) * v;
    t[i][lane] = att * sA + bA;
  }
  __syncthreads();
  const int c = tid >> 2, sub = tid & 3;
  const long plane = ((long)((n << 6) + c)) << 16;
  for (int i = 0; i < 8; ++i) {
    const int pst = (i * 4 + sub) << 2;
    f32x4 vbuf;
#pragma unroll
    for (int j = 0; j < 4; ++j) vbuf[j] = t[pst + j][c];
    *(f32x4*)(&out[plane + hw0 + pst]) = vbuf;
  }
}

extern "C" void kernel_launch(void* const* d_in, const int* in_sizes, int n_in,
                              void* d_out, int out_size, void* d_ws, size_t ws_size,
                              hipStream_t stream) {
  (void)in_sizes; (void)n_in; (void)out_size; (void)ws_size;
  const float* x  = (const float*)d_in[0];
  const float* wq = (const float*)d_in[1];
  const float* gq = (const float*)d_in[2];
  const float* bq = (const float*)d_in[3];
  const float* wk = (const float*)d_in[4];
  const float* gk = (const float*)d_in[5];
  const float* bk = (const float*)d_in[6];
  const float* wv = (const float*)d_in[7];
  const float* gv = (const float*)d_in[8];
  const float* bv = (const float*)d_in[9];
  const float* gn = (const float*)d_in[10];
  const float* bn_ = (const float*)d_in[11];
  char* ws = (char*)d_ws;
  float* S   = (float*)(ws + OFF_SUMS);
  u16* wt    = (u16*)(ws + OFF_WT);
  float* asp = (float*)(ws + OFF_ASP);
  u16* conv  = (u16*)(ws + OFF_CONV);
  float* out = (float*)d_out;
  u16* xt  = (u16*)d_out;  // bf16 NHWC scratch in first half of fp32 out; overwritten by k6_k

  hipMemsetAsync(S, 0, S_NFLOAT * 4, stream);
  transpose_k<<<4096, 256, 0, stream>>>(x, xt);
  repack_k<<<432, 256, 0, stream>>>(wq, wk, wv, wt);
  conv_k<<<4096, 256, 0, stream>>>(xt, wt, conv, S);
  bnparam_k<<<1, 192, 0, stream>>>(S, gq, bq, gk, bk, gv, bv);
  k3_k<<<4096, 256, 0, stream>>>(conv, S, asp);
  k4_k<<<1, 512, 0, stream>>>(S, gn, bn_);
  k6_k<<<4096, 256, 0, stream>>>(conv, S, asp, out);
}